// Round 7
// baseline (91.835 us; speedup 1.0000x reference)
//
#include <hip/hip_runtime.h>

#define SEQ 8192
#define DIM 128
#define QR  4                          // query rows per wave
#define WPB 8                          // waves per block (512 threads)
#define RPB (QR * WPB)                 // 32 rows per block
#define NB  (2 * SEQ / RPB)            // 512 blocks
#define KROWS 96                       // staged K rows: [blkrow0-64, blkrow0+31]

// fp32 in / fp32 out. One wave handles QR=4 consecutive query rows [r0,r0+3];
// lane l owns key j = r0-60+l. Row rr's window is [r0-60, r0+rr] (61..64
// keys); dropped keys carry bias <= -61 -> relative weight < e^-50, invisible
// at fp32. Global sinks (j<100) only matter inside this window (rows i<164),
// where the window covers them.
//
// R7 changes vs R6 (~33us kernel):
//  * XCD-contiguity swizzle: work = (blk&7)*64 + (blk>>3) -> each XCD owns a
//    contiguous 2048-row span; K/V window overlap is served by that XCD's L2
//    instead of re-fetched from HBM by all 8 XCDs.
//  * q staged in LDS -> QK loop is ds_read-only (no s_load/ds_read lgkmcnt
//    mixing; uniform-address q reads broadcast conflict-free).
//  * PV weights via one uniform ds_read_b128 of packed float4 (kills 256
//    v_readlane per wave); PV unrolled 16 for deeper load MLP.
//  * 8 waves/block: staging amortized over 32 query rows.
__global__ __launch_bounds__(512) void lminf_kernel(
    const float* __restrict__ qg,
    const float* __restrict__ kg,
    const float* __restrict__ vg,
    float* __restrict__ og)
{
    const int tid  = threadIdx.x;
    const int lane = tid & 63;
    const int wv   = __builtin_amdgcn_readfirstlane(tid >> 6);  // uniform 0..7

    // XCD-aware remap: dispatch id -> work id, contiguous per XCD
    const int wk      = ((blockIdx.x & 7) << 6) + (blockIdx.x >> 3);
    const int rowblk  = wk * RPB + wv * QR;          // wave's first query row
    const int r0      = rowblk & (SEQ - 1);
    const int blkrow0 = (wk * RPB) & (SEQ - 1);      // block's first row
    const long base   = (long)((wk * RPB) >> 13) * (SEQ * DIM);

    __shared__ float4 kds[KROWS * 32];               // 48 KB, chunk c at c^(row&7)
    __shared__ float  qs[WPB][QR][DIM];              // 16 KB
    __shared__ float4 wsm[WPB][64];                  // 8 KB, per-key packed weights

    // ---- stage K rows [blkrow0-64, blkrow0+31] coalesced, XOR-swizzled ----
    {
        const float4* kgp = (const float4*)(kg + base);
        #pragma unroll
        for (int it = 0; it < (KROWS * 32) / 512; ++it) {   // 6 iters
            const int g   = it * 512 + tid;
            const int row = g >> 5;
            const int c   = g & 31;
            int gr = blkrow0 - 64 + row;
            if (gr < 0) gr = 0;                 // clamped rows never read
            kds[row * 32 + (c ^ (row & 7))] = kgp[gr * 32 + c];
        }
    }
    // ---- stage this wave's 4 q rows (float2 per lane, R5 pattern) ----
    #pragma unroll
    for (int rr = 0; rr < QR; ++rr) {
        const float2 t =
            ((const float2*)(qg + base + (long)(r0 + rr) * DIM))[lane];
        qs[wv][rr][2*lane]   = t.x;
        qs[wv][rr][2*lane+1] = t.y;
    }
    __syncthreads();

    // ---- QK: K via swizzled ds_read_b128; q via uniform (broadcast) reads ----
    const int w0 = r0 - 60;                     // key owned by lane 0
    const int j  = w0 + lane;
    const int lr = lane + wv * QR + 4;          // staged local row of key j
    const int sw = lr & 7;
    const float4* krow = &kds[lr * 32];

    float acc[QR] = {0.f, 0.f, 0.f, 0.f};
    #pragma unroll 8
    for (int c = 0; c < 32; ++c) {
        const float4 kk = krow[c ^ sw];
        #pragma unroll
        for (int rr = 0; rr < QR; ++rr) {
            const float4 qq = ((const float4*)qs[wv][rr])[c];   // uniform addr
            acc[rr] += qq.x * kk.x + qq.y * kk.y + qq.z * kk.z + qq.w * kk.w;
        }
    }

    // ---- softmax per row across 64 lanes (mask -3e38, expf underflow) ----
    float w[QR];
    #pragma unroll
    for (int rr = 0; rr < QR; ++rr) {
        const int i = r0 + rr;
        float s = acc[rr] * 0.08838834764831845f + (float)(j - i);  // bias
        if (j > i || j < 0) s = -3.0e38f;    // causal + left-edge mask
        float m = s;
        #pragma unroll
        for (int off = 32; off; off >>= 1) m = fmaxf(m, __shfl_xor(m, off));
        const float e = __expf(s - m);       // masked lanes -> exact 0
        float l = e;
        #pragma unroll
        for (int off = 32; off; off >>= 1) l += __shfl_xor(l, off);
        w[rr] = e * (1.0f / l);              // l >= 1 (max lane gives 1)
    }
    // lane k holds key w0+k's weights for all 4 rows -> pack to LDS once;
    // same-wave write->read needs only lgkmcnt (compiler inserts), no barrier.
    wsm[wv][lane] = make_float4(w[0], w[1], w[2], w[3]);

    // ---- PV: lane owns dims {2*lane, 2*lane+1}; V coalesced global;
    //      weights via uniform ds_read_b128 broadcast ----
    float o0[QR] = {0.f, 0.f, 0.f, 0.f};
    float o1[QR] = {0.f, 0.f, 0.f, 0.f};
    const float* vb = vg + base;
    #pragma unroll 16
    for (int k = 0; k < 64; ++k) {
        int vr = w0 + k;
        if (vr < 0) vr = 0;                  // clamped rows have weight 0
        const float2 vpair = *(const float2*)(vb + (long)vr * DIM + 2 * lane);
        const float4 wk4 = wsm[wv][k];       // uniform addr -> broadcast
        o0[0] += wk4.x * vpair.x;  o1[0] += wk4.x * vpair.y;
        o0[1] += wk4.y * vpair.x;  o1[1] += wk4.y * vpair.y;
        o0[2] += wk4.z * vpair.x;  o1[2] += wk4.z * vpair.y;
        o0[3] += wk4.w * vpair.x;  o1[3] += wk4.w * vpair.y;
    }

    // ---- store fp32 float2 per lane per row (coalesced) ----
    #pragma unroll
    for (int rr = 0; rr < QR; ++rr) {
        ((float2*)(og + base + (long)(r0 + rr) * DIM))[lane] =
            make_float2(o0[rr], o1[rr]);
    }
}

extern "C" void kernel_launch(void* const* d_in, const int* in_sizes, int n_in,
                              void* d_out, int out_size, void* d_ws, size_t ws_size,
                              hipStream_t stream) {
    const float* q = (const float*)d_in[0];
    const float* k = (const float*)d_in[1];
    const float* v = (const float*)d_in[2];
    float* out = (float*)d_out;

    lminf_kernel<<<NB, 512, 0, stream>>>(q, k, v, out);
}